// Round 3
// baseline (189.962 us; speedup 1.0000x reference)
//
#include <hip/hip_runtime.h>
#include <hip/hip_bf16.h>

#define N_NODES 20000
#define N_EDGES 640000
#define HIDDEN 256
#define HEADS 8
#define HEAD_DIM 32
#define N_FEATS 9
#define VOCAB 119

typedef __hip_bfloat16 bf16;
typedef __attribute__((ext_vector_type(8))) short short8;
typedef __attribute__((ext_vector_type(4))) float f32x4;
typedef __attribute__((ext_vector_type(2))) float f32x2;

__device__ __forceinline__ ushort f2u(float x) { union { ushort u; bf16 b; } c; c.b = __float2bfloat16(x); return c.u; }

// packed f32 math (CDNA: full-rate 2x FMA per instr)
__device__ __forceinline__ f32x2 pk_fma(f32x2 a, f32x2 b, f32x2 c) {
    f32x2 d;
    asm("v_pk_fma_f32 %0, %1, %2, %3" : "=v"(d) : "v"(a), "v"(b), "v"(c));
    return d;
}
__device__ __forceinline__ f32x2 pk_add(f32x2 a, f32x2 b) {
    f32x2 d;
    asm("v_pk_add_f32 %0, %1, %2" : "=v"(d) : "v"(a), "v"(b));
    return d;
}

// DPP cross-lane fetch (VALU pipe, no ds_bpermute latency).
// 0xB1 = quad_perm xor1, 0x4E = quad_perm xor2,
// 0x124 = row_ror:4, 0x128 = row_ror:8 (rotation-reduce within 16-lane rows).
template <int CTRL>
__device__ __forceinline__ float dpp_xor(float v) {
    return __int_as_float(__builtin_amdgcn_update_dpp(
        0, __float_as_int(v), CTRL, 0xf, 0xf, true));
}

__device__ __forceinline__ float fast_exp2(float x) {
#if __has_builtin(__builtin_amdgcn_exp2f)
    return __builtin_amdgcn_exp2f(x);
#else
    return exp2f(x);
#endif
}

// 2-way bf16 dot with f32 accumulate: 1 VALU instr, operands already packed.
#if __has_builtin(__builtin_amdgcn_fdot2_f32_bf16)
typedef __attribute__((ext_vector_type(2))) __bf16 bf16x2_t;
__device__ __forceinline__ float dot2bf(uint a, uint b, float c) {
    return __builtin_amdgcn_fdot2_f32_bf16(__builtin_bit_cast(bf16x2_t, a),
                                           __builtin_bit_cast(bf16x2_t, b), c, false);
}
#else
__device__ __forceinline__ float dot2bf(uint a, uint b, float c) {
    return c + __uint_as_float(a << 16) * __uint_as_float(b << 16)
             + __uint_as_float(a & 0xffff0000u) * __uint_as_float(b & 0xffff0000u);
}
#endif

// ---------------------------------------------------------------- fused pre-work
__global__ void k_pre(const int* __restrict__ X, const float* __restrict__ emb,
                      bf16* __restrict__ h,
                      const float* __restrict__ qw, const float* __restrict__ kw,
                      const float* __restrict__ vw, const float* __restrict__ ow,
                      const float* __restrict__ qb, const float* __restrict__ kb,
                      const float* __restrict__ vb,
                      bf16* __restrict__ wqkv, bf16* __restrict__ wo,
                      float* __restrict__ qkvb,
                      const int* __restrict__ erow, int* __restrict__ row_ptr) {
    int b = blockIdx.x;
    if (b < 5000) {
        int tid = b * 256 + threadIdx.x;
        int n = tid >> 6;
        int c4 = (tid & 63) * 4;
        float4 a = make_float4(0.f, 0.f, 0.f, 0.f);
#pragma unroll
        for (int f = 0; f < N_FEATS; ++f) {
            int idx = X[n * N_FEATS + f];
            float4 e = *(const float4*)(emb + ((size_t)(f * VOCAB + idx)) * HIDDEN + c4);
            a.x += e.x; a.y += e.y; a.z += e.z; a.w += e.w;
        }
        ushort4 o = make_ushort4(f2u(a.x), f2u(a.y), f2u(a.z), f2u(a.w));
        *(ushort4*)((ushort*)h + (size_t)n * HIDDEN + c4) = o;
    } else if (b < 6027) {
        int i = (b - 5000) * 256 + threadIdx.x;     // 262912 total
        if (i < 196608) {
            const float* s = i < 65536 ? qw : i < 131072 ? kw : vw;
            wqkv[i] = __float2bfloat16(s[i & 65535]);
        } else if (i < 262144) {
            wo[i - 196608] = __float2bfloat16(ow[i - 196608]);
        } else if (i < 262912) {
            int j = i - 262144;                      // 768 bias elems
            const float* s = j < 256 ? qb : j < 512 ? kb : vb;
            qkvb[j] = s[j & 255];
        }
    } else {
        int n = (b - 6027) * 256 + threadIdx.x;
        if (n > N_NODES) return;
        int lo = 0, hi = N_EDGES;
        while (lo < hi) {
            int mid = (lo + hi) >> 1;
            if (erow[mid] < n) lo = mid + 1; else hi = mid;
        }
        row_ptr[n] = lo;
    }
}

// ---------------------------------------------------------------- MFMA GEMM core
template <int MODE, bool GUARD, int TM>
__device__ __forceinline__ void gemm_core(const bf16* __restrict__ A,
                                          const bf16* __restrict__ W,
                                          const float* __restrict__ bias,
                                          void* __restrict__ Y0, void* __restrict__ Y1,
                                          float s_q, int n0, int d0) {
    constexpr int RI = TM / 32;          // row subtiles per wave (4 or 2)
    __shared__ short As[TM * 72];
    __shared__ short Bs[128 * 72];
    int t = threadIdx.x;
    int lane = t & 63, w = t >> 6;
    int wr = (w >> 1) * (TM / 2), wc = (w & 1) * 64;
    int lr = lane & 15, quad = lane >> 4;

    f32x4 acc[RI][4] = {};
    short8 ra[RI], rb[4];
    int srowA[RI], skoA[RI], srowB[4], skoB[4];
#pragma unroll
    for (int it = 0; it < RI; ++it) { int c = t + 256 * it; srowA[it] = c >> 3; skoA[it] = (c & 7) * 8; }
#pragma unroll
    for (int it = 0; it < 4; ++it) { int c = t + 256 * it; srowB[it] = c >> 3; skoB[it] = (c & 7) * 8; }

    // prologue: load k0=0, stage to LDS
#pragma unroll
    for (int it = 0; it < RI; ++it) {
        int n = n0 + srowA[it];
        short8 av = {};
        if (!GUARD || n < N_NODES) av = *(const short8*)(A + (size_t)n * HIDDEN + skoA[it]);
        ra[it] = av;
    }
#pragma unroll
    for (int it = 0; it < 4; ++it)
        rb[it] = *(const short8*)(W + (size_t)(d0 + srowB[it]) * HIDDEN + skoB[it]);
#pragma unroll
    for (int it = 0; it < RI; ++it) *(short8*)(&As[srowA[it] * 72 + skoA[it]]) = ra[it];
#pragma unroll
    for (int it = 0; it < 4; ++it)  *(short8*)(&Bs[srowB[it] * 72 + skoB[it]]) = rb[it];
    __syncthreads();

    for (int k0 = 64; k0 < 256; k0 += 64) {
#pragma unroll
        for (int it = 0; it < RI; ++it) {
            int n = n0 + srowA[it];
            short8 av = {};
            if (!GUARD || n < N_NODES) av = *(const short8*)(A + (size_t)n * HIDDEN + k0 + skoA[it]);
            ra[it] = av;
        }
#pragma unroll
        for (int it = 0; it < 4; ++it)
            rb[it] = *(const short8*)(W + (size_t)(d0 + srowB[it]) * HIDDEN + k0 + skoB[it]);
        {
            short8 af[RI][2], bfr[4][2];
#pragma unroll
            for (int i = 0; i < RI; ++i)
#pragma unroll
                for (int kk = 0; kk < 2; ++kk)
                    af[i][kk] = *(short8*)(&As[(wr + i * 16 + lr) * 72 + kk * 32 + quad * 8]);
#pragma unroll
            for (int j = 0; j < 4; ++j)
#pragma unroll
                for (int kk = 0; kk < 2; ++kk)
                    bfr[j][kk] = *(short8*)(&Bs[(wc + j * 16 + lr) * 72 + kk * 32 + quad * 8]);
#pragma unroll
            for (int kk = 0; kk < 2; ++kk)
#pragma unroll
                for (int i = 0; i < RI; ++i)
#pragma unroll
                    for (int j = 0; j < 4; ++j)
                        acc[i][j] = __builtin_amdgcn_mfma_f32_16x16x32_bf16(
                            af[i][kk], bfr[j][kk], acc[i][j], 0, 0, 0);
        }
        __syncthreads();
#pragma unroll
        for (int it = 0; it < RI; ++it) *(short8*)(&As[srowA[it] * 72 + skoA[it]]) = ra[it];
#pragma unroll
        for (int it = 0; it < 4; ++it)  *(short8*)(&Bs[srowB[it] * 72 + skoB[it]]) = rb[it];
        __syncthreads();
    }
    {
        short8 af[RI][2], bfr[4][2];
#pragma unroll
        for (int i = 0; i < RI; ++i)
#pragma unroll
            for (int kk = 0; kk < 2; ++kk)
                af[i][kk] = *(short8*)(&As[(wr + i * 16 + lr) * 72 + kk * 32 + quad * 8]);
#pragma unroll
        for (int j = 0; j < 4; ++j)
#pragma unroll
            for (int kk = 0; kk < 2; ++kk)
                bfr[j][kk] = *(short8*)(&Bs[(wc + j * 16 + lr) * 72 + kk * 32 + quad * 8]);
#pragma unroll
        for (int kk = 0; kk < 2; ++kk)
#pragma unroll
            for (int i = 0; i < RI; ++i)
#pragma unroll
                for (int j = 0; j < 4; ++j)
                    acc[i][j] = __builtin_amdgcn_mfma_f32_16x16x32_bf16(
                        af[i][kk], bfr[j][kk], acc[i][j], 0, 0, 0);
    }

#pragma unroll
    for (int j = 0; j < 4; ++j) {
        int dbase = d0 + wc + j * 16;          // uniform
        float bj = bias[dbase + lr];
        if constexpr (MODE == 0) {
            float sc = (dbase < 256) ? s_q : 1.f;
            ushort* dst; int stride;
            if (dbase < 256) {
                dst = (ushort*)Y0 + (size_t)(dbase >> 6) * N_NODES * 64 + (dbase & 63) + lr;
                stride = 64;
            } else if (dbase < 512) {
                int e = dbase - 256;
                dst = (ushort*)Y1 + (size_t)(e >> 6) * N_NODES * 128 + (e & 63) + lr;
                stride = 128;
            } else {
                int e = dbase - 512;
                dst = (ushort*)Y1 + (size_t)(e >> 6) * N_NODES * 128 + 64 + (e & 63) + lr;
                stride = 128;
            }
#pragma unroll
            for (int i = 0; i < RI; ++i)
#pragma unroll
                for (int r = 0; r < 4; ++r) {
                    int n = n0 + wr + i * 16 + quad * 4 + r;
                    if (GUARD && n >= N_NODES) continue;
                    dst[(size_t)n * stride] = f2u((acc[i][j][r] + bj) * sc);
                }
        } else {
            float* dst = (float*)Y0 + dbase + lr;
#pragma unroll
            for (int i = 0; i < RI; ++i)
#pragma unroll
                for (int r = 0; r < 4; ++r) {
                    int n = n0 + wr + i * 16 + quad * 4 + r;
                    if (GUARD && n >= N_NODES) continue;
                    dst[(size_t)n * HIDDEN] = acc[i][j][r] + bj;
                }
        }
    }
}

__global__ __launch_bounds__(256, 2) void k_gemm_qkv(
    const bf16* __restrict__ A, const bf16* __restrict__ wqkv,
    const float* __restrict__ qkvb, ushort* __restrict__ qhp,
    ushort* __restrict__ kvhp, float qscale) {
    int n0 = blockIdx.x * 128;
    if (n0 + 128 <= N_NODES)
        gemm_core<0, false, 128>(A, wqkv, qkvb, qhp, kvhp, qscale, n0, blockIdx.y * 128);
    else
        gemm_core<0, true, 128>(A, wqkv, qkvb, qhp, kvhp, qscale, n0, blockIdx.y * 128);
}

__global__ __launch_bounds__(256, 4) void k_gemm_o(
    const bf16* __restrict__ A, const bf16* __restrict__ W,
    const float* __restrict__ bias, float* __restrict__ Y) {
    int n0 = blockIdx.x * 64;
    if (n0 + 64 <= N_NODES)
        gemm_core<1, false, 64>(A, W, bias, Y, nullptr, 1.f, n0, blockIdx.y * 128);
    else
        gemm_core<1, true, 64>(A, W, bias, Y, nullptr, 1.f, n0, blockIdx.y * 128);
}

// ---------------------------------------------------------------- fused attention
// R15/R16: lane-per-edge restructure (latency paid once per wave, scores
// lane-local, 1 exp for all edges). R16: wave-uniform n via readfirstlane ->
// row_ptr loads scalarize (s_load) and path B's q loads have uniform
// addresses (SGPR-resident q, ~32 fewer VGPRs in the heaviest path).

// PV accumulate: dims d8*8..+7, unpack bf16 pairs + packed FMA.
template <int NIT>
__device__ __forceinline__ void pv_accum(const uint4* vv, const float* pb,
                                         f32x2& av0, f32x2& av1, f32x2& av2v, f32x2& av3) {
#pragma unroll
    for (int it = 0; it < NIT; ++it) {
        f32x2 pp; pp.x = pb[it]; pp.y = pb[it];
        f32x2 vf0, vf1, vf2, vf3;
        vf0.x = __uint_as_float(vv[it].x << 16); vf0.y = __uint_as_float(vv[it].x & 0xffff0000u);
        vf1.x = __uint_as_float(vv[it].y << 16); vf1.y = __uint_as_float(vv[it].y & 0xffff0000u);
        vf2.x = __uint_as_float(vv[it].z << 16); vf2.y = __uint_as_float(vv[it].z & 0xffff0000u);
        vf3.x = __uint_as_float(vv[it].w << 16); vf3.y = __uint_as_float(vv[it].w & 0xffff0000u);
        av0  = pk_fma(vf0, pp, av0);
        av1  = pk_fma(vf1, pp, av1);
        av2v = pk_fma(vf2, pp, av2v);
        av3  = pk_fma(vf3, pp, av3);
    }
}

// reduce-scatter combine over edge-slot bits 3..5; lane stores dim
// d8*8 + b3*4 + b4*2 + b5.
__device__ __forceinline__ void attn_combine(int lane, int d8, float z,
                                             f32x2 av0, f32x2 av1, f32x2 av2v, f32x2 av3,
                                             ushort* __restrict__ orow) {
    bool b3 = (lane & 8) != 0, b4 = (lane & 16) != 0, b5 = (lane & 32) != 0;
    f32x2 sd0 = b3 ? av0 : av2v;
    f32x2 sd1 = b3 ? av1 : av3;
    f32x2 r0, r1;
    r0.x = dpp_xor<0x128>(sd0.x); r0.y = dpp_xor<0x128>(sd0.y);
    r1.x = dpp_xor<0x128>(sd1.x); r1.y = dpp_xor<0x128>(sd1.y);
    f32x2 t0 = pk_add(b3 ? av2v : av0, r0);
    f32x2 t1 = pk_add(b3 ? av3  : av1, r1);
    f32x2 sdu = b4 ? t0 : t1;
    f32x2 ru; ru.x = __shfl_xor(sdu.x, 16); ru.y = __shfl_xor(sdu.y, 16);
    f32x2 u = pk_add(b4 ? t1 : t0, ru);
    float sw = b5 ? u.x : u.y;
    float rw = __shfl_xor(sw, 32);
    float w = (b5 ? u.y : u.x) + rw;
    int dim = d8 * 8 + ((lane >> 3) & 1) * 4 + ((lane >> 4) & 1) * 2 + ((lane >> 5) & 1);
    orow[dim] = f2u(w * (1.f / z));
}

__global__ __launch_bounds__(256, 4) void k_attn(
    const int* __restrict__ row_ptr, const int* __restrict__ col,
    const ushort* __restrict__ qhp, const ushort* __restrict__ kvhp,
    bf16* __restrict__ agg) {
    int b = blockIdx.x;
    int x = b & 7;
    int hp = x & 3;
    // wave-uniform: lets the compiler scalarize row_ptr loads + base addrs
    int wave = __builtin_amdgcn_readfirstlane((int)(threadIdx.x >> 6));
    int n = (b >> 3) * 8 + (x >> 2) * 4 + wave;
    int lane = threadIdx.x & 63;
    int my = lane >> 3;          // PV edge slot 0..7
    int d8 = lane & 7;           // PV dim slot (head = d8>>2)

    int start = row_ptr[n];
    int deg = row_ptr[n + 1] - start;

    ushort* orow = (ushort*)agg + (size_t)n * HIDDEN + hp * 64;
    if (deg == 0) {
        if (lane < 8) { uint4 zo = {}; *(uint4*)(orow + lane * 8) = zo; }
        return;
    }

    const ushort* qrow = qhp + ((size_t)hp * N_NODES + n) * 64;   // log2e pre-scaled
    const ushort* kvbase = kvhp + (size_t)hp * N_NODES * 128;
    const int* cb = col + start;

    if (deg <= 32) {
        // ---- path A: 64 lanes = 32 edges x 2 heads; one stall per wave ----
        int e = lane >> 1, h = lane & 1;
        int c_e = cb[min(e, deg - 1)];
        const ushort* kp = kvbase + (((size_t)(uint)c_e) << 7) + (uint)h * 32;
        const ushort* qp = qrow + (uint)h * 32;

        // PV cols + V loads, all upfront (clamped cols are valid rows; dead
        // edges contribute p=0)
        int cv[4]; uint4 vv[4];
#pragma unroll
        for (int it = 0; it < 4; ++it) cv[it] = __shfl(c_e, (it * 8 + my) * 2);
#pragma unroll
        for (int it = 0; it < 4; ++it)
            vv[it] = *(const uint4*)(kvbase + (((size_t)(uint)cv[it]) << 7) + 64 + (uint)d8 * 8);

        uint4 kk[4], qq[4];
#pragma unroll
        for (int i = 0; i < 4; ++i) kk[i] = *(const uint4*)(kp + i * 8);
#pragma unroll
        for (int i = 0; i < 4; ++i) qq[i] = *(const uint4*)(qp + i * 8);

        // lane-local score: 16 dot2bf in 4 chains, no cross-lane reduce
        float c0 = dot2bf(kk[0].x, qq[0].x, 0.f);
        float c1 = dot2bf(kk[0].y, qq[0].y, 0.f);
        float c2 = dot2bf(kk[0].z, qq[0].z, 0.f);
        float c3 = dot2bf(kk[0].w, qq[0].w, 0.f);
#pragma unroll
        for (int i = 1; i < 4; ++i) {
            c0 = dot2bf(kk[i].x, qq[i].x, c0);
            c1 = dot2bf(kk[i].y, qq[i].y, c1);
            c2 = dot2bf(kk[i].z, qq[i].z, c2);
            c3 = dot2bf(kk[i].w, qq[i].w, c3);
        }
        float s = (c0 + c1) + (c2 + c3);
        float p = (e < deg) ? fast_exp2(s) : 0.f;

        // z per head: parity classes reduce independently under xor>=2
        float z = p;
        z += dpp_xor<0x4E>(z);
        z += dpp_xor<0x124>(z);
        z += dpp_xor<0x128>(z);
        z += __shfl_xor(z, 16);
        z += __shfl_xor(z, 32);
        float zo = __shfl_xor(z, 1);
        float zf = (h == (d8 >> 2)) ? z : zo;

        // p redistribute: 1 bpermute/iter (source lane = edge*2 + wanted head)
        float pb[4];
#pragma unroll
        for (int it = 0; it < 4; ++it)
            pb[it] = __shfl(p, (it * 8 + my) * 2 + (d8 >> 2));

        f32x2 av0 = {0.f, 0.f}, av1 = {0.f, 0.f}, av2v = {0.f, 0.f}, av3 = {0.f, 0.f};
        pv_accum<4>(vv, pb, av0, av1, av2v, av3);
        attn_combine(lane, d8, zf, av0, av1, av2v, av3, orow);

    } else if (deg <= 64) {
        // ---- path B: lane-per-edge, both heads per lane ----
        int c_all = cb[min(lane, deg - 1)];
        const ushort* kp = kvbase + (((size_t)(uint)c_all) << 7);

        int cv[8]; uint4 vv[8];
#pragma unroll
        for (int it = 0; it < 8; ++it) cv[it] = __shfl(c_all, it * 8 + my);
#pragma unroll
        for (int it = 0; it < 8; ++it)
            vv[it] = *(const uint4*)(kvbase + (((size_t)(uint)cv[it]) << 7) + 64 + (uint)d8 * 8);

        uint4 kk[8], qv[8];
#pragma unroll
        for (int i = 0; i < 8; ++i) kk[i] = *(const uint4*)(kp + i * 8);
        // uniform address (n, hp wave-uniform) -> scalar loads, q lives in SGPRs
#pragma unroll
        for (int i = 0; i < 8; ++i) qv[i] = *(const uint4*)(qrow + i * 8);

        float a0 = dot2bf(kk[0].x, qv[0].x, 0.f);
        float a1 = dot2bf(kk[0].y, qv[0].y, 0.f);
        float a2 = dot2bf(kk[0].z, qv[0].z, 0.f);
        float a3 = dot2bf(kk[0].w, qv[0].w, 0.f);
        float b0 = dot2bf(kk[4].x, qv[4].x, 0.f);
        float b1 = dot2bf(kk[4].y, qv[4].y, 0.f);
        float b2 = dot2bf(kk[4].z, qv[4].z, 0.f);
        float b3s = dot2bf(kk[4].w, qv[4].w, 0.f);
#pragma unroll
        for (int i = 1; i < 4; ++i) {
            a0 = dot2bf(kk[i].x, qv[i].x, a0);
            a1 = dot2bf(kk[i].y, qv[i].y, a1);
            a2 = dot2bf(kk[i].z, qv[i].z, a2);
            a3 = dot2bf(kk[i].w, qv[i].w, a3);
            b0 = dot2bf(kk[4 + i].x, qv[4 + i].x, b0);
            b1 = dot2bf(kk[4 + i].y, qv[4 + i].y, b1);
            b2 = dot2bf(kk[4 + i].z, qv[4 + i].z, b2);
            b3s = dot2bf(kk[4 + i].w, qv[4 + i].w, b3s);
        }
        float sA = (a0 + a1) + (a2 + a3);
        float sB = (b0 + b1) + (b2 + b3s);
        bool val = lane < deg;
        float pA = val ? fast_exp2(sA) : 0.f;
        float pB = val ? fast_exp2(sB) : 0.f;

        // z for both heads, packed butterfly over all 64 lanes
        f32x2 zz; zz.x = pA; zz.y = pB;
        {
            f32x2 r;
            r.x = dpp_xor<0xB1>(zz.x);  r.y = dpp_xor<0xB1>(zz.y);  zz = pk_add(zz, r);
            r.x = dpp_xor<0x4E>(zz.x);  r.y = dpp_xor<0x4E>(zz.y);  zz = pk_add(zz, r);
            r.x = dpp_xor<0x124>(zz.x); r.y = dpp_xor<0x124>(zz.y); zz = pk_add(zz, r);
            r.x = dpp_xor<0x128>(zz.x); r.y = dpp_xor<0x128>(zz.y); zz = pk_add(zz, r);
            r.x = __shfl_xor(zz.x, 16); r.y = __shfl_xor(zz.y, 16); zz = pk_add(zz, r);
            r.x = __shfl_xor(zz.x, 32); r.y = __shfl_xor(zz.y, 32); zz = pk_add(zz, r);
        }
        float zf = (d8 < 4) ? zz.x : zz.y;

        bool hB = (d8 >= 4);
        float pb[8];
#pragma unroll
        for (int it = 0; it < 8; ++it) {
            float pa_ = __shfl(pA, it * 8 + my);
            float pb_ = __shfl(pB, it * 8 + my);
            pb[it] = hB ? pb_ : pa_;
        }

        f32x2 av0 = {0.f, 0.f}, av1 = {0.f, 0.f}, av2v = {0.f, 0.f}, av3 = {0.f, 0.f};
        pv_accum<8>(vv, pb, av0, av1, av2v, av3);
        attn_combine(lane, d8, zf, av0, av1, av2v, av3, orow);

    } else {
        // ---- fallback deg > 64 (Poisson(32): ~never) : dim-parallel loop ----
        uint4 qu = *(const uint4*)(qrow + d8 * 8);
        float z = 0.f;
        f32x2 av0 = {0.f, 0.f}, av1 = {0.f, 0.f}, av2v = {0.f, 0.f}, av3 = {0.f, 0.f};
        for (int i = 0; i < deg; i += 8) {
            int idx = i + my;
            int cidx = idx < deg ? idx : deg - 1;
            int c = cb[cidx];
            const ushort* kp = kvbase + (((size_t)(uint)c) << 7) + (uint)d8 * 8;
            uint4 ku = *(const uint4*)(kp);
            uint4 vu = *(const uint4*)(kp + 64);
            float s = dot2bf(ku.x, qu.x, 0.f);
            s = dot2bf(ku.y, qu.y, s);
            s = dot2bf(ku.z, qu.z, s);
            s = dot2bf(ku.w, qu.w, s);
            s += dpp_xor<0xB1>(s);
            s += dpp_xor<0x4E>(s);
            float p = (idx < deg) ? fast_exp2(s) : 0.f;
            z += p;
            f32x2 pp; pp.x = p; pp.y = p;
            f32x2 vf0, vf1, vf2, vf3;
            vf0.x = __uint_as_float(vu.x << 16); vf0.y = __uint_as_float(vu.x & 0xffff0000u);
            vf1.x = __uint_as_float(vu.y << 16); vf1.y = __uint_as_float(vu.y & 0xffff0000u);
            vf2.x = __uint_as_float(vu.z << 16); vf2.y = __uint_as_float(vu.z & 0xffff0000u);
            vf3.x = __uint_as_float(vu.w << 16); vf3.y = __uint_as_float(vu.w & 0xffff0000u);
            av0  = pk_fma(vf0, pp, av0);
            av1  = pk_fma(vf1, pp, av1);
            av2v = pk_fma(vf2, pp, av2v);
            av3  = pk_fma(vf3, pp, av3);
        }
        z += dpp_xor<0x128>(z);
        z += __shfl_xor(z, 16);
        z += __shfl_xor(z, 32);
        attn_combine(lane, d8, z, av0, av1, av2v, av3, orow);
    }
}

// ---------------------------------------------------------------- launch
extern "C" void kernel_launch(void* const* d_in, const int* in_sizes, int n_in,
                              void* d_out, int out_size, void* d_ws, size_t ws_size,
                              hipStream_t stream) {
    const int*   X    = (const int*)d_in[0];
    const int*   erow = (const int*)d_in[1];
    const int*   ecol = (const int*)d_in[2];
    const float* emb  = (const float*)d_in[3];
    const float* q_w  = (const float*)d_in[4];
    const float* q_b  = (const float*)d_in[5];
    const float* k_w  = (const float*)d_in[6];
    const float* k_b  = (const float*)d_in[7];
    const float* v_w  = (const float*)d_in[8];
    const float* v_b  = (const float*)d_in[9];
    const float* o_w  = (const float*)d_in[10];
    const float* o_b  = (const float*)d_in[11];
    float* out = (float*)d_out;

    char* ws = (char*)d_ws;
    bf16*   h    = (bf16*)(ws);
    bf16*   agg  = (bf16*)(ws);                 // aliases h (dead after QKV GEMM)
    ushort* qhp  = (ushort*)(ws + 10240000);
    ushort* kvhp = (ushort*)(ws + 20480000);
    bf16*   wqkv = (bf16*)(ws + 40960000);
    bf16*   wo   = (bf16*)(ws + 41353216);
    float*  qkvb = (float*)(ws + 41484288);
    int* row_ptr = (int*)(ws + 41487360);

    k_pre<<<6106, 256, 0, stream>>>(X, emb, h, q_w, k_w, v_w, o_w,
                                    q_b, k_b, v_b, wqkv, wo, qkvb, erow, row_ptr);

    // 1/sqrt(32) * log2(e): scores in log2 domain -> raw v_exp_f32 in k_attn.
    const float qscale = 0.25503486121587466f;
    dim3 gqkv((N_NODES + 127) / 128, 768 / 128);
    k_gemm_qkv<<<gqkv, 256, 0, stream>>>(h, wqkv, qkvb, qhp, kvhp, qscale);

    k_attn<<<N_NODES, 256, 0, stream>>>(row_ptr, ecol, qhp, kvhp, agg);

    dim3 go((N_NODES + 63) / 64, HIDDEN / 128);
    k_gemm_o<<<go, 256, 0, stream>>>(agg, wo, o_b, out);
}

// Round 4
// 186.075 us; speedup vs baseline: 1.0209x; 1.0209x over previous
//
#include <hip/hip_runtime.h>
#include <hip/hip_bf16.h>

#define N_NODES 20000
#define N_EDGES 640000
#define HIDDEN 256
#define HEADS 8
#define HEAD_DIM 32
#define N_FEATS 9
#define VOCAB 119

typedef __hip_bfloat16 bf16;
typedef __attribute__((ext_vector_type(8))) short short8;
typedef __attribute__((ext_vector_type(4))) float f32x4;
typedef __attribute__((ext_vector_type(2))) float f32x2;

__device__ __forceinline__ ushort f2u(float x) { union { ushort u; bf16 b; } c; c.b = __float2bfloat16(x); return c.u; }

// packed f32 math (CDNA: full-rate 2x FMA per instr)
__device__ __forceinline__ f32x2 pk_fma(f32x2 a, f32x2 b, f32x2 c) {
    f32x2 d;
    asm("v_pk_fma_f32 %0, %1, %2, %3" : "=v"(d) : "v"(a), "v"(b), "v"(c));
    return d;
}
__device__ __forceinline__ f32x2 pk_add(f32x2 a, f32x2 b) {
    f32x2 d;
    asm("v_pk_add_f32 %0, %1, %2" : "=v"(d) : "v"(a), "v"(b));
    return d;
}

// DPP cross-lane fetch (VALU pipe, no ds_bpermute latency).
// 0xB1 = quad_perm xor1, 0x4E = quad_perm xor2,
// 0x124 = row_ror:4, 0x128 = row_ror:8 (rotation-reduce within 16-lane rows).
template <int CTRL>
__device__ __forceinline__ float dpp_xor(float v) {
    return __int_as_float(__builtin_amdgcn_update_dpp(
        0, __float_as_int(v), CTRL, 0xf, 0xf, true));
}

__device__ __forceinline__ float fast_exp2(float x) {
#if __has_builtin(__builtin_amdgcn_exp2f)
    return __builtin_amdgcn_exp2f(x);
#else
    return exp2f(x);
#endif
}

// hard scheduling fence: nothing moves across (pins "issue all loads, then
// compute" so the compiler can't sink loads next to uses — R3's failure mode)
__device__ __forceinline__ void sched_fence() {
    __builtin_amdgcn_sched_barrier(0);
}

// 2-way bf16 dot with f32 accumulate: 1 VALU instr, operands already packed.
#if __has_builtin(__builtin_amdgcn_fdot2_f32_bf16)
typedef __attribute__((ext_vector_type(2))) __bf16 bf16x2_t;
__device__ __forceinline__ float dot2bf(uint a, uint b, float c) {
    return __builtin_amdgcn_fdot2_f32_bf16(__builtin_bit_cast(bf16x2_t, a),
                                           __builtin_bit_cast(bf16x2_t, b), c, false);
}
#else
__device__ __forceinline__ float dot2bf(uint a, uint b, float c) {
    return c + __uint_as_float(a << 16) * __uint_as_float(b << 16)
             + __uint_as_float(a & 0xffff0000u) * __uint_as_float(b & 0xffff0000u);
}
#endif

// ---------------------------------------------------------------- fused pre-work
__global__ void k_pre(const int* __restrict__ X, const float* __restrict__ emb,
                      bf16* __restrict__ h,
                      const float* __restrict__ qw, const float* __restrict__ kw,
                      const float* __restrict__ vw, const float* __restrict__ ow,
                      const float* __restrict__ qb, const float* __restrict__ kb,
                      const float* __restrict__ vb,
                      bf16* __restrict__ wqkv, bf16* __restrict__ wo,
                      float* __restrict__ qkvb,
                      const int* __restrict__ erow, int* __restrict__ row_ptr) {
    int b = blockIdx.x;
    if (b < 5000) {
        int tid = b * 256 + threadIdx.x;
        int n = tid >> 6;
        int c4 = (tid & 63) * 4;
        float4 a = make_float4(0.f, 0.f, 0.f, 0.f);
#pragma unroll
        for (int f = 0; f < N_FEATS; ++f) {
            int idx = X[n * N_FEATS + f];
            float4 e = *(const float4*)(emb + ((size_t)(f * VOCAB + idx)) * HIDDEN + c4);
            a.x += e.x; a.y += e.y; a.z += e.z; a.w += e.w;
        }
        ushort4 o = make_ushort4(f2u(a.x), f2u(a.y), f2u(a.z), f2u(a.w));
        *(ushort4*)((ushort*)h + (size_t)n * HIDDEN + c4) = o;
    } else if (b < 6027) {
        int i = (b - 5000) * 256 + threadIdx.x;     // 262912 total
        if (i < 196608) {
            const float* s = i < 65536 ? qw : i < 131072 ? kw : vw;
            wqkv[i] = __float2bfloat16(s[i & 65535]);
        } else if (i < 262144) {
            wo[i - 196608] = __float2bfloat16(ow[i - 196608]);
        } else if (i < 262912) {
            int j = i - 262144;                      // 768 bias elems
            const float* s = j < 256 ? qb : j < 512 ? kb : vb;
            qkvb[j] = s[j & 255];
        }
    } else {
        int n = (b - 6027) * 256 + threadIdx.x;
        if (n > N_NODES) return;
        int lo = 0, hi = N_EDGES;
        while (lo < hi) {
            int mid = (lo + hi) >> 1;
            if (erow[mid] < n) lo = mid + 1; else hi = mid;
        }
        row_ptr[n] = lo;
    }
}

// ---------------------------------------------------------------- MFMA GEMM core
template <int MODE, bool GUARD, int TM>
__device__ __forceinline__ void gemm_core(const bf16* __restrict__ A,
                                          const bf16* __restrict__ W,
                                          const float* __restrict__ bias,
                                          void* __restrict__ Y0, void* __restrict__ Y1,
                                          float s_q, int n0, int d0) {
    constexpr int RI = TM / 32;          // row subtiles per wave (4 or 2)
    __shared__ short As[TM * 72];
    __shared__ short Bs[128 * 72];
    int t = threadIdx.x;
    int lane = t & 63, w = t >> 6;
    int wr = (w >> 1) * (TM / 2), wc = (w & 1) * 64;
    int lr = lane & 15, quad = lane >> 4;

    f32x4 acc[RI][4] = {};
    short8 ra[RI], rb[4];
    int srowA[RI], skoA[RI], srowB[4], skoB[4];
#pragma unroll
    for (int it = 0; it < RI; ++it) { int c = t + 256 * it; srowA[it] = c >> 3; skoA[it] = (c & 7) * 8; }
#pragma unroll
    for (int it = 0; it < 4; ++it) { int c = t + 256 * it; srowB[it] = c >> 3; skoB[it] = (c & 7) * 8; }

    // prologue: load k0=0, stage to LDS
#pragma unroll
    for (int it = 0; it < RI; ++it) {
        int n = n0 + srowA[it];
        short8 av = {};
        if (!GUARD || n < N_NODES) av = *(const short8*)(A + (size_t)n * HIDDEN + skoA[it]);
        ra[it] = av;
    }
#pragma unroll
    for (int it = 0; it < 4; ++it)
        rb[it] = *(const short8*)(W + (size_t)(d0 + srowB[it]) * HIDDEN + skoB[it]);
#pragma unroll
    for (int it = 0; it < RI; ++it) *(short8*)(&As[srowA[it] * 72 + skoA[it]]) = ra[it];
#pragma unroll
    for (int it = 0; it < 4; ++it)  *(short8*)(&Bs[srowB[it] * 72 + skoB[it]]) = rb[it];
    __syncthreads();

    for (int k0 = 64; k0 < 256; k0 += 64) {
#pragma unroll
        for (int it = 0; it < RI; ++it) {
            int n = n0 + srowA[it];
            short8 av = {};
            if (!GUARD || n < N_NODES) av = *(const short8*)(A + (size_t)n * HIDDEN + k0 + skoA[it]);
            ra[it] = av;
        }
#pragma unroll
        for (int it = 0; it < 4; ++it)
            rb[it] = *(const short8*)(W + (size_t)(d0 + srowB[it]) * HIDDEN + k0 + skoB[it]);
        {
            short8 af[RI][2], bfr[4][2];
#pragma unroll
            for (int i = 0; i < RI; ++i)
#pragma unroll
                for (int kk = 0; kk < 2; ++kk)
                    af[i][kk] = *(short8*)(&As[(wr + i * 16 + lr) * 72 + kk * 32 + quad * 8]);
#pragma unroll
            for (int j = 0; j < 4; ++j)
#pragma unroll
                for (int kk = 0; kk < 2; ++kk)
                    bfr[j][kk] = *(short8*)(&Bs[(wc + j * 16 + lr) * 72 + kk * 32 + quad * 8]);
#pragma unroll
            for (int kk = 0; kk < 2; ++kk)
#pragma unroll
                for (int i = 0; i < RI; ++i)
#pragma unroll
                    for (int j = 0; j < 4; ++j)
                        acc[i][j] = __builtin_amdgcn_mfma_f32_16x16x32_bf16(
                            af[i][kk], bfr[j][kk], acc[i][j], 0, 0, 0);
        }
        __syncthreads();
#pragma unroll
        for (int it = 0; it < RI; ++it) *(short8*)(&As[srowA[it] * 72 + skoA[it]]) = ra[it];
#pragma unroll
        for (int it = 0; it < 4; ++it)  *(short8*)(&Bs[srowB[it] * 72 + skoB[it]]) = rb[it];
        __syncthreads();
    }
    {
        short8 af[RI][2], bfr[4][2];
#pragma unroll
        for (int i = 0; i < RI; ++i)
#pragma unroll
            for (int kk = 0; kk < 2; ++kk)
                af[i][kk] = *(short8*)(&As[(wr + i * 16 + lr) * 72 + kk * 32 + quad * 8]);
#pragma unroll
        for (int j = 0; j < 4; ++j)
#pragma unroll
            for (int kk = 0; kk < 2; ++kk)
                bfr[j][kk] = *(short8*)(&Bs[(wc + j * 16 + lr) * 72 + kk * 32 + quad * 8]);
#pragma unroll
        for (int kk = 0; kk < 2; ++kk)
#pragma unroll
            for (int i = 0; i < RI; ++i)
#pragma unroll
                for (int j = 0; j < 4; ++j)
                    acc[i][j] = __builtin_amdgcn_mfma_f32_16x16x32_bf16(
                        af[i][kk], bfr[j][kk], acc[i][j], 0, 0, 0);
    }

#pragma unroll
    for (int j = 0; j < 4; ++j) {
        int dbase = d0 + wc + j * 16;          // uniform
        float bj = bias[dbase + lr];
        if constexpr (MODE == 0) {
            float sc = (dbase < 256) ? s_q : 1.f;
            ushort* dst; int stride;
            if (dbase < 256) {
                dst = (ushort*)Y0 + (size_t)(dbase >> 6) * N_NODES * 64 + (dbase & 63) + lr;
                stride = 64;
            } else if (dbase < 512) {
                int e = dbase - 256;
                dst = (ushort*)Y1 + (size_t)(e >> 6) * N_NODES * 128 + (e & 63) + lr;
                stride = 128;
            } else {
                int e = dbase - 512;
                dst = (ushort*)Y1 + (size_t)(e >> 6) * N_NODES * 128 + 64 + (e & 63) + lr;
                stride = 128;
            }
#pragma unroll
            for (int i = 0; i < RI; ++i)
#pragma unroll
                for (int r = 0; r < 4; ++r) {
                    int n = n0 + wr + i * 16 + quad * 4 + r;
                    if (GUARD && n >= N_NODES) continue;
                    dst[(size_t)n * stride] = f2u((acc[i][j][r] + bj) * sc);
                }
        } else {
            float* dst = (float*)Y0 + dbase + lr;
#pragma unroll
            for (int i = 0; i < RI; ++i)
#pragma unroll
                for (int r = 0; r < 4; ++r) {
                    int n = n0 + wr + i * 16 + quad * 4 + r;
                    if (GUARD && n >= N_NODES) continue;
                    dst[(size_t)n * HIDDEN] = acc[i][j][r] + bj;
                }
        }
    }
}

__global__ __launch_bounds__(256, 2) void k_gemm_qkv(
    const bf16* __restrict__ A, const bf16* __restrict__ wqkv,
    const float* __restrict__ qkvb, ushort* __restrict__ qhp,
    ushort* __restrict__ kvhp, float qscale) {
    int n0 = blockIdx.x * 128;
    if (n0 + 128 <= N_NODES)
        gemm_core<0, false, 128>(A, wqkv, qkvb, qhp, kvhp, qscale, n0, blockIdx.y * 128);
    else
        gemm_core<0, true, 128>(A, wqkv, qkvb, qhp, kvhp, qscale, n0, blockIdx.y * 128);
}

__global__ __launch_bounds__(256, 4) void k_gemm_o(
    const bf16* __restrict__ A, const bf16* __restrict__ W,
    const float* __restrict__ bias, float* __restrict__ Y) {
    int n0 = blockIdx.x * 64;
    if (n0 + 64 <= N_NODES)
        gemm_core<1, false, 64>(A, W, bias, Y, nullptr, 1.f, n0, blockIdx.y * 128);
    else
        gemm_core<1, true, 64>(A, W, bias, Y, nullptr, 1.f, n0, blockIdx.y * 128);
}

// ---------------------------------------------------------------- fused attention
// R15-R17: lane-per-edge, latency paid once per wave. R17: the load batch is
// PINNED with sched_barrier(0) — R3 showed the scheduler otherwise sinks each
// load to its first use (VGPR=36, re-serialized chain, 63us). The fence forces
// all K/V/q loads in flight before any score math.

// PV accumulate: dims d8*8..+7, unpack bf16 pairs + packed FMA.
template <int NIT>
__device__ __forceinline__ void pv_accum(const uint4* vv, const float* pb,
                                         f32x2& av0, f32x2& av1, f32x2& av2v, f32x2& av3) {
#pragma unroll
    for (int it = 0; it < NIT; ++it) {
        f32x2 pp; pp.x = pb[it]; pp.y = pb[it];
        f32x2 vf0, vf1, vf2, vf3;
        vf0.x = __uint_as_float(vv[it].x << 16); vf0.y = __uint_as_float(vv[it].x & 0xffff0000u);
        vf1.x = __uint_as_float(vv[it].y << 16); vf1.y = __uint_as_float(vv[it].y & 0xffff0000u);
        vf2.x = __uint_as_float(vv[it].z << 16); vf2.y = __uint_as_float(vv[it].z & 0xffff0000u);
        vf3.x = __uint_as_float(vv[it].w << 16); vf3.y = __uint_as_float(vv[it].w & 0xffff0000u);
        av0  = pk_fma(vf0, pp, av0);
        av1  = pk_fma(vf1, pp, av1);
        av2v = pk_fma(vf2, pp, av2v);
        av3  = pk_fma(vf3, pp, av3);
    }
}

// reduce-scatter combine over edge-slot bits 3..5; lane stores dim
// d8*8 + b3*4 + b4*2 + b5.
__device__ __forceinline__ void attn_combine(int lane, int d8, float z,
                                             f32x2 av0, f32x2 av1, f32x2 av2v, f32x2 av3,
                                             ushort* __restrict__ orow) {
    bool b3 = (lane & 8) != 0, b4 = (lane & 16) != 0, b5 = (lane & 32) != 0;
    f32x2 sd0 = b3 ? av0 : av2v;
    f32x2 sd1 = b3 ? av1 : av3;
    f32x2 r0, r1;
    r0.x = dpp_xor<0x128>(sd0.x); r0.y = dpp_xor<0x128>(sd0.y);
    r1.x = dpp_xor<0x128>(sd1.x); r1.y = dpp_xor<0x128>(sd1.y);
    f32x2 t0 = pk_add(b3 ? av2v : av0, r0);
    f32x2 t1 = pk_add(b3 ? av3  : av1, r1);
    f32x2 sdu = b4 ? t0 : t1;
    f32x2 ru; ru.x = __shfl_xor(sdu.x, 16); ru.y = __shfl_xor(sdu.y, 16);
    f32x2 u = pk_add(b4 ? t1 : t0, ru);
    float sw = b5 ? u.x : u.y;
    float rw = __shfl_xor(sw, 32);
    float w = (b5 ? u.y : u.x) + rw;
    int dim = d8 * 8 + ((lane >> 3) & 1) * 4 + ((lane >> 4) & 1) * 2 + ((lane >> 5) & 1);
    orow[dim] = f2u(w * (1.f / z));
}

__global__ __launch_bounds__(256, 4) void k_attn(
    const int* __restrict__ row_ptr, const int* __restrict__ col,
    const ushort* __restrict__ qhp, const ushort* __restrict__ kvhp,
    bf16* __restrict__ agg) {
    int b = blockIdx.x;
    int x = b & 7;
    int hp = x & 3;
    // wave-uniform: lets the compiler scalarize row_ptr loads + base addrs
    int wave = __builtin_amdgcn_readfirstlane((int)(threadIdx.x >> 6));
    int n = (b >> 3) * 8 + (x >> 2) * 4 + wave;
    int lane = threadIdx.x & 63;
    int my = lane >> 3;          // PV edge slot 0..7
    int d8 = lane & 7;           // PV dim slot (head = d8>>2)

    int start = row_ptr[n];
    int deg = row_ptr[n + 1] - start;

    ushort* orow = (ushort*)agg + (size_t)n * HIDDEN + hp * 64;
    if (deg == 0) {
        if (lane < 8) { uint4 zo = {}; *(uint4*)(orow + lane * 8) = zo; }
        return;
    }

    const ushort* qrow = qhp + ((size_t)hp * N_NODES + n) * 64;   // log2e pre-scaled
    const ushort* kvbase = kvhp + (size_t)hp * N_NODES * 128;
    const int* cb = col + start;

    if (deg <= 32) {
        // ---- path A: 64 lanes = 32 edges x 2 heads; one stall per wave ----
        int e = lane >> 1, h = lane & 1;
        const ushort* qp = qrow + (uint)h * 32;

        // independent loads first: q (no deps) + edge col
        uint4 qq[4];
#pragma unroll
        for (int i = 0; i < 4; ++i) qq[i] = *(const uint4*)(qp + i * 8);
        int c_e = cb[min(e, deg - 1)];

        // dependent: cv via bpermute, then K + V batch
        int cv[4];
#pragma unroll
        for (int it = 0; it < 4; ++it) cv[it] = __shfl(c_e, (it * 8 + my) * 2);
        const ushort* kp = kvbase + (((size_t)(uint)c_e) << 7) + (uint)h * 32;
        uint4 kk[4], vv[4];
#pragma unroll
        for (int i = 0; i < 4; ++i) kk[i] = *(const uint4*)(kp + i * 8);
#pragma unroll
        for (int it = 0; it < 4; ++it)
            vv[it] = *(const uint4*)(kvbase + (((size_t)(uint)cv[it]) << 7) + 64 + (uint)d8 * 8);

        sched_fence();   // ALL loads issued before any compute

        // lane-local score: 16 dot2bf in 4 chains, no cross-lane reduce
        float c0 = dot2bf(kk[0].x, qq[0].x, 0.f);
        float c1 = dot2bf(kk[0].y, qq[0].y, 0.f);
        float c2 = dot2bf(kk[0].z, qq[0].z, 0.f);
        float c3 = dot2bf(kk[0].w, qq[0].w, 0.f);
#pragma unroll
        for (int i = 1; i < 4; ++i) {
            c0 = dot2bf(kk[i].x, qq[i].x, c0);
            c1 = dot2bf(kk[i].y, qq[i].y, c1);
            c2 = dot2bf(kk[i].z, qq[i].z, c2);
            c3 = dot2bf(kk[i].w, qq[i].w, c3);
        }
        float s = (c0 + c1) + (c2 + c3);
        float p = (e < deg) ? fast_exp2(s) : 0.f;

        // z per head: parity classes reduce independently under xor>=2
        float z = p;
        z += dpp_xor<0x4E>(z);
        z += dpp_xor<0x124>(z);
        z += dpp_xor<0x128>(z);
        z += __shfl_xor(z, 16);
        z += __shfl_xor(z, 32);
        float zo = __shfl_xor(z, 1);
        float zf = (h == (d8 >> 2)) ? z : zo;

        // p redistribute: 1 bpermute/iter (source lane = edge*2 + wanted head)
        float pb[4];
#pragma unroll
        for (int it = 0; it < 4; ++it)
            pb[it] = __shfl(p, (it * 8 + my) * 2 + (d8 >> 2));

        f32x2 av0 = {0.f, 0.f}, av1 = {0.f, 0.f}, av2v = {0.f, 0.f}, av3 = {0.f, 0.f};
        pv_accum<4>(vv, pb, av0, av1, av2v, av3);
        attn_combine(lane, d8, zf, av0, av1, av2v, av3, orow);

    } else if (deg <= 64) {
        // ---- path B: lane-per-edge, both heads per lane ----
        // q loads have a wave-uniform address -> scalar loads (SGPR), free of
        // the VGPR batch budget
        uint4 qv[8];
#pragma unroll
        for (int i = 0; i < 8; ++i) qv[i] = *(const uint4*)(qrow + i * 8);
        int c_all = cb[min(lane, deg - 1)];

        int cv[8];
#pragma unroll
        for (int it = 0; it < 8; ++it) cv[it] = __shfl(c_all, it * 8 + my);
        const ushort* kp = kvbase + (((size_t)(uint)c_all) << 7);
        uint4 kk[8], vv[8];
#pragma unroll
        for (int i = 0; i < 8; ++i) kk[i] = *(const uint4*)(kp + i * 8);
#pragma unroll
        for (int it = 0; it < 8; ++it)
            vv[it] = *(const uint4*)(kvbase + (((size_t)(uint)cv[it]) << 7) + 64 + (uint)d8 * 8);

        sched_fence();   // ALL loads issued before any compute

        float a0 = dot2bf(kk[0].x, qv[0].x, 0.f);
        float a1 = dot2bf(kk[0].y, qv[0].y, 0.f);
        float a2 = dot2bf(kk[0].z, qv[0].z, 0.f);
        float a3 = dot2bf(kk[0].w, qv[0].w, 0.f);
        float b0 = dot2bf(kk[4].x, qv[4].x, 0.f);
        float b1 = dot2bf(kk[4].y, qv[4].y, 0.f);
        float b2 = dot2bf(kk[4].z, qv[4].z, 0.f);
        float b3s = dot2bf(kk[4].w, qv[4].w, 0.f);
#pragma unroll
        for (int i = 1; i < 4; ++i) {
            a0 = dot2bf(kk[i].x, qv[i].x, a0);
            a1 = dot2bf(kk[i].y, qv[i].y, a1);
            a2 = dot2bf(kk[i].z, qv[i].z, a2);
            a3 = dot2bf(kk[i].w, qv[i].w, a3);
            b0 = dot2bf(kk[4 + i].x, qv[4 + i].x, b0);
            b1 = dot2bf(kk[4 + i].y, qv[4 + i].y, b1);
            b2 = dot2bf(kk[4 + i].z, qv[4 + i].z, b2);
            b3s = dot2bf(kk[4 + i].w, qv[4 + i].w, b3s);
        }
        float sA = (a0 + a1) + (a2 + a3);
        float sB = (b0 + b1) + (b2 + b3s);
        bool val = lane < deg;
        float pA = val ? fast_exp2(sA) : 0.f;
        float pB = val ? fast_exp2(sB) : 0.f;

        // z for both heads, packed butterfly over all 64 lanes
        f32x2 zz; zz.x = pA; zz.y = pB;
        {
            f32x2 r;
            r.x = dpp_xor<0xB1>(zz.x);  r.y = dpp_xor<0xB1>(zz.y);  zz = pk_add(zz, r);
            r.x = dpp_xor<0x4E>(zz.x);  r.y = dpp_xor<0x4E>(zz.y);  zz = pk_add(zz, r);
            r.x = dpp_xor<0x124>(zz.x); r.y = dpp_xor<0x124>(zz.y); zz = pk_add(zz, r);
            r.x = dpp_xor<0x128>(zz.x); r.y = dpp_xor<0x128>(zz.y); zz = pk_add(zz, r);
            r.x = __shfl_xor(zz.x, 16); r.y = __shfl_xor(zz.y, 16); zz = pk_add(zz, r);
            r.x = __shfl_xor(zz.x, 32); r.y = __shfl_xor(zz.y, 32); zz = pk_add(zz, r);
        }
        float zf = (d8 < 4) ? zz.x : zz.y;

        bool hB = (d8 >= 4);
        float pb[8];
#pragma unroll
        for (int it = 0; it < 8; ++it) {
            float pa_ = __shfl(pA, it * 8 + my);
            float pb_ = __shfl(pB, it * 8 + my);
            pb[it] = hB ? pb_ : pa_;
        }

        f32x2 av0 = {0.f, 0.f}, av1 = {0.f, 0.f}, av2v = {0.f, 0.f}, av3 = {0.f, 0.f};
        pv_accum<8>(vv, pb, av0, av1, av2v, av3);
        attn_combine(lane, d8, zf, av0, av1, av2v, av3, orow);

    } else {
        // ---- fallback deg > 64 (Poisson(32): ~never) : dim-parallel loop ----
        uint4 qu = *(const uint4*)(qrow + d8 * 8);
        float z = 0.f;
        f32x2 av0 = {0.f, 0.f}, av1 = {0.f, 0.f}, av2v = {0.f, 0.f}, av3 = {0.f, 0.f};
        for (int i = 0; i < deg; i += 8) {
            int idx = i + my;
            int cidx = idx < deg ? idx : deg - 1;
            int c = cb[cidx];
            const ushort* kp = kvbase + (((size_t)(uint)c) << 7) + (uint)d8 * 8;
            uint4 ku = *(const uint4*)(kp);
            uint4 vu = *(const uint4*)(kp + 64);
            float s = dot2bf(ku.x, qu.x, 0.f);
            s = dot2bf(ku.y, qu.y, s);
            s = dot2bf(ku.z, qu.z, s);
            s = dot2bf(ku.w, qu.w, s);
            s += dpp_xor<0xB1>(s);
            s += dpp_xor<0x4E>(s);
            float p = (idx < deg) ? fast_exp2(s) : 0.f;
            z += p;
            f32x2 pp; pp.x = p; pp.y = p;
            f32x2 vf0, vf1, vf2, vf3;
            vf0.x = __uint_as_float(vu.x << 16); vf0.y = __uint_as_float(vu.x & 0xffff0000u);
            vf1.x = __uint_as_float(vu.y << 16); vf1.y = __uint_as_float(vu.y & 0xffff0000u);
            vf2.x = __uint_as_float(vu.z << 16); vf2.y = __uint_as_float(vu.z & 0xffff0000u);
            vf3.x = __uint_as_float(vu.w << 16); vf3.y = __uint_as_float(vu.w & 0xffff0000u);
            av0  = pk_fma(vf0, pp, av0);
            av1  = pk_fma(vf1, pp, av1);
            av2v = pk_fma(vf2, pp, av2v);
            av3  = pk_fma(vf3, pp, av3);
        }
        z += dpp_xor<0x128>(z);
        z += __shfl_xor(z, 16);
        z += __shfl_xor(z, 32);
        attn_combine(lane, d8, z, av0, av1, av2v, av3, orow);
    }
}

// ---------------------------------------------------------------- launch
extern "C" void kernel_launch(void* const* d_in, const int* in_sizes, int n_in,
                              void* d_out, int out_size, void* d_ws, size_t ws_size,
                              hipStream_t stream) {
    const int*   X    = (const int*)d_in[0];
    const int*   erow = (const int*)d_in[1];
    const int*   ecol = (const int*)d_in[2];
    const float* emb  = (const float*)d_in[3];
    const float* q_w  = (const float*)d_in[4];
    const float* q_b  = (const float*)d_in[5];
    const float* k_w  = (const float*)d_in[6];
    const float* k_b  = (const float*)d_in[7];
    const float* v_w  = (const float*)d_in[8];
    const float* v_b  = (const float*)d_in[9];
    const float* o_w  = (const float*)d_in[10];
    const float* o_b  = (const float*)d_in[11];
    float* out = (float*)d_out;

    char* ws = (char*)d_ws;
    bf16*   h    = (bf16*)(ws);
    bf16*   agg  = (bf16*)(ws);                 // aliases h (dead after QKV GEMM)
    ushort* qhp  = (ushort*)(ws + 10240000);
    ushort* kvhp = (ushort*)(ws + 20480000);
    bf16*   wqkv = (bf16*)(ws + 40960000);
    bf16*   wo   = (bf16*)(ws + 41353216);
    float*  qkvb = (float*)(ws + 41484288);
    int* row_ptr = (int*)(ws + 41487360);

    k_pre<<<6106, 256, 0, stream>>>(X, emb, h, q_w, k_w, v_w, o_w,
                                    q_b, k_b, v_b, wqkv, wo, qkvb, erow, row_ptr);

    // 1/sqrt(32) * log2(e): scores in log2 domain -> raw v_exp_f32 in k_attn.
    const float qscale = 0.25503486121587466f;
    dim3 gqkv((N_NODES + 127) / 128, 768 / 128);
    k_gemm_qkv<<<gqkv, 256, 0, stream>>>(h, wqkv, qkvb, qhp, kvhp, qscale);

    k_attn<<<N_NODES, 256, 0, stream>>>(row_ptr, ecol, qhp, kvhp, agg);

    dim3 go((N_NODES + 63) / 64, HIDDEN / 128);
    k_gemm_o<<<go, 256, 0, stream>>>(agg, wo, o_b, out);
}

// Round 5
// 172.688 us; speedup vs baseline: 1.1000x; 1.0775x over previous
//
#include <hip/hip_runtime.h>
#include <hip/hip_bf16.h>

#define N_NODES 20000
#define N_EDGES 640000
#define HIDDEN 256
#define HEADS 8
#define HEAD_DIM 32
#define N_FEATS 9
#define VOCAB 119

typedef __hip_bfloat16 bf16;
typedef __attribute__((ext_vector_type(8))) short short8;
typedef __attribute__((ext_vector_type(4))) float f32x4;
typedef __attribute__((ext_vector_type(2))) float f32x2;

__device__ __forceinline__ ushort f2u(float x) { union { ushort u; bf16 b; } c; c.b = __float2bfloat16(x); return c.u; }

// packed f32 math (CDNA: full-rate 2x FMA per instr)
__device__ __forceinline__ f32x2 pk_fma(f32x2 a, f32x2 b, f32x2 c) {
    f32x2 d;
    asm("v_pk_fma_f32 %0, %1, %2, %3" : "=v"(d) : "v"(a), "v"(b), "v"(c));
    return d;
}
__device__ __forceinline__ f32x2 pk_add(f32x2 a, f32x2 b) {
    f32x2 d;
    asm("v_pk_add_f32 %0, %1, %2" : "=v"(d) : "v"(a), "v"(b));
    return d;
}

// DPP cross-lane fetch (VALU pipe, no ds_bpermute latency).
// 0xB1 = quad_perm xor1, 0x4E = quad_perm xor2, 0x128 = row_ror:8 (== xor 8
// within a 16-lane row for reduction purposes).
template <int CTRL>
__device__ __forceinline__ float dpp_xor(float v) {
    return __int_as_float(__builtin_amdgcn_update_dpp(
        0, __float_as_int(v), CTRL, 0xf, 0xf, true));
}

__device__ __forceinline__ float fast_exp2(float x) {
#if __has_builtin(__builtin_amdgcn_exp2f)
    return __builtin_amdgcn_exp2f(x);
#else
    return exp2f(x);
#endif
}

// hard scheduling fence: nothing moves across (pins "issue all loads, then
// compute" so the compiler can't sink loads next to uses)
__device__ __forceinline__ void sched_fence() {
    __builtin_amdgcn_sched_barrier(0);
}

// 2-way bf16 dot with f32 accumulate: 1 VALU instr, operands already packed.
#if __has_builtin(__builtin_amdgcn_fdot2_f32_bf16)
typedef __attribute__((ext_vector_type(2))) __bf16 bf16x2_t;
__device__ __forceinline__ float dot2bf(uint a, uint b, float c) {
    return __builtin_amdgcn_fdot2_f32_bf16(__builtin_bit_cast(bf16x2_t, a),
                                           __builtin_bit_cast(bf16x2_t, b), c, false);
}
#else
__device__ __forceinline__ float dot2bf(uint a, uint b, float c) {
    return c + __uint_as_float(a << 16) * __uint_as_float(b << 16)
             + __uint_as_float(a & 0xffff0000u) * __uint_as_float(b & 0xffff0000u);
}
#endif

// ---------------------------------------------------------------- fused pre-work
__global__ void k_pre(const int* __restrict__ X, const float* __restrict__ emb,
                      bf16* __restrict__ h,
                      const float* __restrict__ qw, const float* __restrict__ kw,
                      const float* __restrict__ vw, const float* __restrict__ ow,
                      const float* __restrict__ qb, const float* __restrict__ kb,
                      const float* __restrict__ vb,
                      bf16* __restrict__ wqkv, bf16* __restrict__ wo,
                      float* __restrict__ qkvb,
                      const int* __restrict__ erow, int* __restrict__ row_ptr) {
    int b = blockIdx.x;
    if (b < 5000) {
        int tid = b * 256 + threadIdx.x;
        int n = tid >> 6;
        int c4 = (tid & 63) * 4;
        float4 a = make_float4(0.f, 0.f, 0.f, 0.f);
#pragma unroll
        for (int f = 0; f < N_FEATS; ++f) {
            int idx = X[n * N_FEATS + f];
            float4 e = *(const float4*)(emb + ((size_t)(f * VOCAB + idx)) * HIDDEN + c4);
            a.x += e.x; a.y += e.y; a.z += e.z; a.w += e.w;
        }
        ushort4 o = make_ushort4(f2u(a.x), f2u(a.y), f2u(a.z), f2u(a.w));
        *(ushort4*)((ushort*)h + (size_t)n * HIDDEN + c4) = o;
    } else if (b < 6027) {
        int i = (b - 5000) * 256 + threadIdx.x;     // 262912 total
        if (i < 196608) {
            const float* s = i < 65536 ? qw : i < 131072 ? kw : vw;
            wqkv[i] = __float2bfloat16(s[i & 65535]);
        } else if (i < 262144) {
            wo[i - 196608] = __float2bfloat16(ow[i - 196608]);
        } else if (i < 262912) {
            int j = i - 262144;                      // 768 bias elems
            const float* s = j < 256 ? qb : j < 512 ? kb : vb;
            qkvb[j] = s[j & 255];
        }
    } else {
        int n = (b - 6027) * 256 + threadIdx.x;
        if (n > N_NODES) return;
        int lo = 0, hi = N_EDGES;
        while (lo < hi) {
            int mid = (lo + hi) >> 1;
            if (erow[mid] < n) lo = mid + 1; else hi = mid;
        }
        row_ptr[n] = lo;
    }
}

// ---------------------------------------------------------------- MFMA GEMM core
template <int MODE, bool GUARD, int TM>
__device__ __forceinline__ void gemm_core(const bf16* __restrict__ A,
                                          const bf16* __restrict__ W,
                                          const float* __restrict__ bias,
                                          void* __restrict__ Y0, void* __restrict__ Y1,
                                          float s_q, int n0, int d0) {
    constexpr int RI = TM / 32;          // row subtiles per wave (4 or 2)
    __shared__ short As[TM * 72];
    __shared__ short Bs[128 * 72];
    int t = threadIdx.x;
    int lane = t & 63, w = t >> 6;
    int wr = (w >> 1) * (TM / 2), wc = (w & 1) * 64;
    int lr = lane & 15, quad = lane >> 4;

    f32x4 acc[RI][4] = {};
    short8 ra[RI], rb[4];
    int srowA[RI], skoA[RI], srowB[4], skoB[4];
#pragma unroll
    for (int it = 0; it < RI; ++it) { int c = t + 256 * it; srowA[it] = c >> 3; skoA[it] = (c & 7) * 8; }
#pragma unroll
    for (int it = 0; it < 4; ++it) { int c = t + 256 * it; srowB[it] = c >> 3; skoB[it] = (c & 7) * 8; }

    // prologue: load k0=0, stage to LDS
#pragma unroll
    for (int it = 0; it < RI; ++it) {
        int n = n0 + srowA[it];
        short8 av = {};
        if (!GUARD || n < N_NODES) av = *(const short8*)(A + (size_t)n * HIDDEN + skoA[it]);
        ra[it] = av;
    }
#pragma unroll
    for (int it = 0; it < 4; ++it)
        rb[it] = *(const short8*)(W + (size_t)(d0 + srowB[it]) * HIDDEN + skoB[it]);
#pragma unroll
    for (int it = 0; it < RI; ++it) *(short8*)(&As[srowA[it] * 72 + skoA[it]]) = ra[it];
#pragma unroll
    for (int it = 0; it < 4; ++it)  *(short8*)(&Bs[srowB[it] * 72 + skoB[it]]) = rb[it];
    __syncthreads();

    for (int k0 = 64; k0 < 256; k0 += 64) {
#pragma unroll
        for (int it = 0; it < RI; ++it) {
            int n = n0 + srowA[it];
            short8 av = {};
            if (!GUARD || n < N_NODES) av = *(const short8*)(A + (size_t)n * HIDDEN + k0 + skoA[it]);
            ra[it] = av;
        }
#pragma unroll
        for (int it = 0; it < 4; ++it)
            rb[it] = *(const short8*)(W + (size_t)(d0 + srowB[it]) * HIDDEN + k0 + skoB[it]);
        {
            short8 af[RI][2], bfr[4][2];
#pragma unroll
            for (int i = 0; i < RI; ++i)
#pragma unroll
                for (int kk = 0; kk < 2; ++kk)
                    af[i][kk] = *(short8*)(&As[(wr + i * 16 + lr) * 72 + kk * 32 + quad * 8]);
#pragma unroll
            for (int j = 0; j < 4; ++j)
#pragma unroll
                for (int kk = 0; kk < 2; ++kk)
                    bfr[j][kk] = *(short8*)(&Bs[(wc + j * 16 + lr) * 72 + kk * 32 + quad * 8]);
#pragma unroll
            for (int kk = 0; kk < 2; ++kk)
#pragma unroll
                for (int i = 0; i < RI; ++i)
#pragma unroll
                    for (int j = 0; j < 4; ++j)
                        acc[i][j] = __builtin_amdgcn_mfma_f32_16x16x32_bf16(
                            af[i][kk], bfr[j][kk], acc[i][j], 0, 0, 0);
        }
        __syncthreads();
#pragma unroll
        for (int it = 0; it < RI; ++it) *(short8*)(&As[srowA[it] * 72 + skoA[it]]) = ra[it];
#pragma unroll
        for (int it = 0; it < 4; ++it)  *(short8*)(&Bs[srowB[it] * 72 + skoB[it]]) = rb[it];
        __syncthreads();
    }
    {
        short8 af[RI][2], bfr[4][2];
#pragma unroll
        for (int i = 0; i < RI; ++i)
#pragma unroll
            for (int kk = 0; kk < 2; ++kk)
                af[i][kk] = *(short8*)(&As[(wr + i * 16 + lr) * 72 + kk * 32 + quad * 8]);
#pragma unroll
        for (int j = 0; j < 4; ++j)
#pragma unroll
            for (int kk = 0; kk < 2; ++kk)
                bfr[j][kk] = *(short8*)(&Bs[(wc + j * 16 + lr) * 72 + kk * 32 + quad * 8]);
#pragma unroll
        for (int kk = 0; kk < 2; ++kk)
#pragma unroll
            for (int i = 0; i < RI; ++i)
#pragma unroll
                for (int j = 0; j < 4; ++j)
                    acc[i][j] = __builtin_amdgcn_mfma_f32_16x16x32_bf16(
                        af[i][kk], bfr[j][kk], acc[i][j], 0, 0, 0);
    }

#pragma unroll
    for (int j = 0; j < 4; ++j) {
        int dbase = d0 + wc + j * 16;          // uniform
        float bj = bias[dbase + lr];
        if constexpr (MODE == 0) {
            float sc = (dbase < 256) ? s_q : 1.f;
            ushort* dst; int stride;
            if (dbase < 256) {
                dst = (ushort*)Y0 + (size_t)(dbase >> 6) * N_NODES * 64 + (dbase & 63) + lr;
                stride = 64;
            } else if (dbase < 512) {
                int e = dbase - 256;
                dst = (ushort*)Y1 + (size_t)(e >> 6) * N_NODES * 128 + (e & 63) + lr;
                stride = 128;
            } else {
                int e = dbase - 512;
                dst = (ushort*)Y1 + (size_t)(e >> 6) * N_NODES * 128 + 64 + (e & 63) + lr;
                stride = 128;
            }
#pragma unroll
            for (int i = 0; i < RI; ++i)
#pragma unroll
                for (int r = 0; r < 4; ++r) {
                    int n = n0 + wr + i * 16 + quad * 4 + r;
                    if (GUARD && n >= N_NODES) continue;
                    dst[(size_t)n * stride] = f2u((acc[i][j][r] + bj) * sc);
                }
        } else {
            float* dst = (float*)Y0 + dbase + lr;
#pragma unroll
            for (int i = 0; i < RI; ++i)
#pragma unroll
                for (int r = 0; r < 4; ++r) {
                    int n = n0 + wr + i * 16 + quad * 4 + r;
                    if (GUARD && n >= N_NODES) continue;
                    dst[(size_t)n * HIDDEN] = acc[i][j][r] + bj;
                }
        }
    }
}

__global__ __launch_bounds__(256, 2) void k_gemm_qkv(
    const bf16* __restrict__ A, const bf16* __restrict__ wqkv,
    const float* __restrict__ qkvb, ushort* __restrict__ qhp,
    ushort* __restrict__ kvhp, float qscale) {
    int n0 = blockIdx.x * 128;
    if (n0 + 128 <= N_NODES)
        gemm_core<0, false, 128>(A, wqkv, qkvb, qhp, kvhp, qscale, n0, blockIdx.y * 128);
    else
        gemm_core<0, true, 128>(A, wqkv, qkvb, qhp, kvhp, qscale, n0, blockIdx.y * 128);
}

__global__ __launch_bounds__(256, 4) void k_gemm_o(
    const bf16* __restrict__ A, const bf16* __restrict__ W,
    const float* __restrict__ bias, float* __restrict__ Y) {
    int n0 = blockIdx.x * 64;
    if (n0 + 64 <= N_NODES)
        gemm_core<1, false, 64>(A, W, bias, Y, nullptr, 1.f, n0, blockIdx.y * 128);
    else
        gemm_core<1, true, 64>(A, W, bias, Y, nullptr, 1.f, n0, blockIdx.y * 128);
}

// ---------------------------------------------------------------- fused attention
// R18: transaction-optimal layout + batched loads.
// kvhp row = 256B = 2 cache lines (K-half line 0, V-half line 1). The R1
// layout (lane = (edge-slot my, dim-chunk d8), 8 edges x 8 chunks per instr)
// touches each line exactly ONCE per wave with 8 contiguous lanes per line
// (8 txns/instr). R15-R17's lane-per-edge K pattern re-requested each K line
// 4x (64 txns/instr, ~288/wave) -> L2-transaction-bound at ~61us. R18 = R1
// math (quad-DPP score reduce, p naturally resident in the PV lane, no
// redistribution) with ALL loads hoisted upfront: one latency exposure per
// wave, K issued before V so score compute drains vmcnt progressively while
// V stays in flight.

// PV accumulate: dims d8*8..+7, unpack bf16 pairs + packed FMA.
template <int NIT>
__device__ __forceinline__ void pv_accum(const uint4* vv, const float* pb,
                                         f32x2& av0, f32x2& av1, f32x2& av2v, f32x2& av3) {
#pragma unroll
    for (int it = 0; it < NIT; ++it) {
        f32x2 pp; pp.x = pb[it]; pp.y = pb[it];
        f32x2 vf0, vf1, vf2, vf3;
        vf0.x = __uint_as_float(vv[it].x << 16); vf0.y = __uint_as_float(vv[it].x & 0xffff0000u);
        vf1.x = __uint_as_float(vv[it].y << 16); vf1.y = __uint_as_float(vv[it].y & 0xffff0000u);
        vf2.x = __uint_as_float(vv[it].z << 16); vf2.y = __uint_as_float(vv[it].z & 0xffff0000u);
        vf3.x = __uint_as_float(vv[it].w << 16); vf3.y = __uint_as_float(vv[it].w & 0xffff0000u);
        av0  = pk_fma(vf0, pp, av0);
        av1  = pk_fma(vf1, pp, av1);
        av2v = pk_fma(vf2, pp, av2v);
        av3  = pk_fma(vf3, pp, av3);
    }
}

// reduce-scatter combine over edge-slot bits 3..5; lane stores dim
// d8*8 + b3*4 + b4*2 + b5.
__device__ __forceinline__ void attn_combine(int lane, int d8, float z,
                                             f32x2 av0, f32x2 av1, f32x2 av2v, f32x2 av3,
                                             ushort* __restrict__ orow) {
    bool b3 = (lane & 8) != 0, b4 = (lane & 16) != 0, b5 = (lane & 32) != 0;
    f32x2 sd0 = b3 ? av0 : av2v;
    f32x2 sd1 = b3 ? av1 : av3;
    f32x2 r0, r1;
    r0.x = dpp_xor<0x128>(sd0.x); r0.y = dpp_xor<0x128>(sd0.y);
    r1.x = dpp_xor<0x128>(sd1.x); r1.y = dpp_xor<0x128>(sd1.y);
    f32x2 t0 = pk_add(b3 ? av2v : av0, r0);
    f32x2 t1 = pk_add(b3 ? av3  : av1, r1);
    f32x2 sdu = b4 ? t0 : t1;
    f32x2 ru; ru.x = __shfl_xor(sdu.x, 16); ru.y = __shfl_xor(sdu.y, 16);
    f32x2 u = pk_add(b4 ? t1 : t0, ru);
    float sw = b5 ? u.x : u.y;
    float rw = __shfl_xor(sw, 32);
    float w = (b5 ? u.y : u.x) + rw;
    int dim = d8 * 8 + ((lane >> 3) & 1) * 4 + ((lane >> 4) & 1) * 2 + ((lane >> 5) & 1);
    orow[dim] = f2u(w * (1.f / z));
}

// one-shot dense path: NIT*8 edge slots, all K/V lines touched exactly once.
template <int NIT>
__device__ __forceinline__ void attn_dense(const int* __restrict__ cb, int deg,
                                           int lane, int my, int d8,
                                           const ushort* __restrict__ qrow,
                                           const ushort* __restrict__ kvbase,
                                           ushort* __restrict__ orow) {
    int degm8 = deg - my;                 // edge it*8+my valid iff it*8 < degm8
    int c_all = cb[min(lane, deg - 1)];   // clamped cols are valid rows
    uint d8b = (uint)d8 * 8;

    int cc[NIT];
#pragma unroll
    for (int it = 0; it < NIT; ++it) cc[it] = __shfl(c_all, it * 8 + my);

    uint4 qu = *(const uint4*)(qrow + d8b);   // 1 line, broadcast across my-groups
    uint4 kk[NIT], vv[NIT];
#pragma unroll
    for (int it = 0; it < NIT; ++it)          // K first: scores drain vmcnt early
        kk[it] = *(const uint4*)(kvbase + (((size_t)(uint)cc[it]) << 7) + d8b);
#pragma unroll
    for (int it = 0; it < NIT; ++it)          // V stays in flight during scores
        vv[it] = *(const uint4*)(kvbase + (((size_t)(uint)cc[it]) << 7) + 64 + d8b);

    sched_fence();                            // all loads issued before compute

    float z = 0.f;
    float pb[NIT];
#pragma unroll
    for (int it = 0; it < NIT; ++it) {
        float s = dot2bf(kk[it].x, qu.x, 0.f);
        s = dot2bf(kk[it].y, qu.y, s);
        s = dot2bf(kk[it].z, qu.z, s);
        s = dot2bf(kk[it].w, qu.w, s);
        s += dpp_xor<0xB1>(s);                // quad reduce over d8 bits 0,1:
        s += dpp_xor<0x4E>(s);                // full 32-dim score for head d8>>2
        float p = (it * 8 < degm8) ? fast_exp2(s) : 0.f;
        z += p;
        pb[it] = p;                           // p already in the right PV lane
    }
    z += dpp_xor<0x128>(z);                   // reduce over edge-slot bits 3..5
    z += __shfl_xor(z, 16);
    z += __shfl_xor(z, 32);

    f32x2 av0 = {0.f, 0.f}, av1 = {0.f, 0.f}, av2v = {0.f, 0.f}, av3 = {0.f, 0.f};
    pv_accum<NIT>(vv, pb, av0, av1, av2v, av3);
    attn_combine(lane, d8, z, av0, av1, av2v, av3, orow);
}

__global__ __launch_bounds__(256, 4) void k_attn(
    const int* __restrict__ row_ptr, const int* __restrict__ col,
    const ushort* __restrict__ qhp, const ushort* __restrict__ kvhp,
    bf16* __restrict__ agg) {
    int b = blockIdx.x;
    int x = b & 7;
    int hp = x & 3;
    // wave-uniform: lets the compiler scalarize row_ptr loads + base addrs
    int wave = __builtin_amdgcn_readfirstlane((int)(threadIdx.x >> 6));
    int n = (b >> 3) * 8 + (x >> 2) * 4 + wave;
    int lane = threadIdx.x & 63;
    int my = lane >> 3;          // edge slot 0..7
    int d8 = lane & 7;           // dim chunk (head = d8>>2)

    int start = row_ptr[n];
    int deg = row_ptr[n + 1] - start;

    ushort* orow = (ushort*)agg + (size_t)n * HIDDEN + hp * 64;
    if (deg == 0) {
        if (lane < 8) { uint4 zo = {}; *(uint4*)(orow + lane * 8) = zo; }
        return;
    }

    const ushort* qrow = qhp + ((size_t)hp * N_NODES + n) * 64;   // log2e pre-scaled
    const ushort* kvbase = kvhp + (size_t)hp * N_NODES * 128;
    const int* cb = col + start;

    if (deg <= 32) {
        attn_dense<4>(cb, deg, lane, my, d8, qrow, kvbase, orow);
    } else if (deg <= 64) {
        attn_dense<8>(cb, deg, lane, my, d8, qrow, kvbase, orow);
    } else {
        // ---- fallback deg > 64 (Poisson(32): ~never) : dim-parallel loop ----
        uint4 qu = *(const uint4*)(qrow + d8 * 8);
        float z = 0.f;
        f32x2 av0 = {0.f, 0.f}, av1 = {0.f, 0.f}, av2v = {0.f, 0.f}, av3 = {0.f, 0.f};
        for (int i = 0; i < deg; i += 8) {
            int idx = i + my;
            int cidx = idx < deg ? idx : deg - 1;
            int c = cb[cidx];
            const ushort* kp = kvbase + (((size_t)(uint)c) << 7) + (uint)d8 * 8;
            uint4 ku = *(const uint4*)(kp);
            uint4 vu = *(const uint4*)(kp + 64);
            float s = dot2bf(ku.x, qu.x, 0.f);
            s = dot2bf(ku.y, qu.y, s);
            s = dot2bf(ku.z, qu.z, s);
            s = dot2bf(ku.w, qu.w, s);
            s += dpp_xor<0xB1>(s);
            s += dpp_xor<0x4E>(s);
            float p = (idx < deg) ? fast_exp2(s) : 0.f;
            z += p;
            f32x2 pp; pp.x = p; pp.y = p;
            f32x2 vf0, vf1, vf2, vf3;
            vf0.x = __uint_as_float(vu.x << 16); vf0.y = __uint_as_float(vu.x & 0xffff0000u);
            vf1.x = __uint_as_float(vu.y << 16); vf1.y = __uint_as_float(vu.y & 0xffff0000u);
            vf2.x = __uint_as_float(vu.z << 16); vf2.y = __uint_as_float(vu.z & 0xffff0000u);
            vf3.x = __uint_as_float(vu.w << 16); vf3.y = __uint_as_float(vu.w & 0xffff0000u);
            av0  = pk_fma(vf0, pp, av0);
            av1  = pk_fma(vf1, pp, av1);
            av2v = pk_fma(vf2, pp, av2v);
            av3  = pk_fma(vf3, pp, av3);
        }
        z += dpp_xor<0x128>(z);
        z += __shfl_xor(z, 16);
        z += __shfl_xor(z, 32);
        attn_combine(lane, d8, z, av0, av1, av2v, av3, orow);
    }
}

// ---------------------------------------------------------------- launch
extern "C" void kernel_launch(void* const* d_in, const int* in_sizes, int n_in,
                              void* d_out, int out_size, void* d_ws, size_t ws_size,
                              hipStream_t stream) {
    const int*   X    = (const int*)d_in[0];
    const int*   erow = (const int*)d_in[1];
    const int*   ecol = (const int*)d_in[2];
    const float* emb  = (const float*)d_in[3];
    const float* q_w  = (const float*)d_in[4];
    const float* q_b  = (const float*)d_in[5];
    const float* k_w  = (const float*)d_in[6];
    const float* k_b  = (const float*)d_in[7];
    const float* v_w  = (const float*)d_in[8];
    const float* v_b  = (const float*)d_in[9];
    const float* o_w  = (const float*)d_in[10];
    const float* o_b  = (const float*)d_in[11];
    float* out = (float*)d_out;

    char* ws = (char*)d_ws;
    bf16*   h    = (bf16*)(ws);
    bf16*   agg  = (bf16*)(ws);                 // aliases h (dead after QKV GEMM)
    ushort* qhp  = (ushort*)(ws + 10240000);
    ushort* kvhp = (ushort*)(ws + 20480000);
    bf16*   wqkv = (bf16*)(ws + 40960000);
    bf16*   wo   = (bf16*)(ws + 41353216);
    float*  qkvb = (float*)(ws + 41484288);
    int* row_ptr = (int*)(ws + 41487360);

    k_pre<<<6106, 256, 0, stream>>>(X, emb, h, q_w, k_w, v_w, o_w,
                                    q_b, k_b, v_b, wqkv, wo, qkvb, erow, row_ptr);

    // 1/sqrt(32) * log2(e): scores in log2 domain -> raw v_exp_f32 in k_attn.
    const float qscale = 0.25503486121587466f;
    dim3 gqkv((N_NODES + 127) / 128, 768 / 128);
    k_gemm_qkv<<<gqkv, 256, 0, stream>>>(h, wqkv, qkvb, qhp, kvhp, qscale);

    k_attn<<<N_NODES, 256, 0, stream>>>(row_ptr, ecol, qhp, kvhp, agg);

    dim3 go((N_NODES + 63) / 64, HIDDEN / 128);
    k_gemm_o<<<go, 256, 0, stream>>>(agg, wo, o_b, out);
}